// Round 15
// baseline (239.769 us; speedup 1.0000x reference)
//
#include <hip/hip_runtime.h>
#include <hip/hip_bf16.h>

#define B_  32
#define S_  512
#define D_  768
#define H_  12
#define HD_ 64
#define QKV_ELEMS (B_ * H_ * S_ * HD_)  // 12582912 per tensor

typedef __hip_bfloat16 bf16;
typedef short bf16x8_t __attribute__((ext_vector_type(8)));
typedef float f32x4_t  __attribute__((ext_vector_type(4)));

__device__ __forceinline__ float bf2f(bf16 x) { return __bfloat162float(x); }
__device__ __forceinline__ bf16  f2bf(float x) { return __float2bfloat16(x); }

__device__ __forceinline__ void gl_lds16(const short* g, short* l) {
    __builtin_amdgcn_global_load_lds(
        (const __attribute__((address_space(1))) void*)g,
        (__attribute__((address_space(3))) void*)l, 16, 0, 0);
}

// ---------------------------------------------------------------------------
// fused fp32 -> bf16 conversion, GRID-STRIDED (G11: memory-bound op capped
// at 2048 blocks; 14592 tiny blocks -> 2048 blocks x ~7 float4 each).
// Loop body and segment routing unchanged from the verified r14 version.
// (r12 lesson: standalone BW-bound pass beats in-GEMM sync fusion.)
// ---------------------------------------------------------------------------
__global__ __launch_bounds__(256) void f2bf3_kernel(
    const float* __restrict__ in0, unsigned short* __restrict__ out0, int n0,
    const float* __restrict__ in1, unsigned short* __restrict__ out1, int n1,
    const float* __restrict__ in2, unsigned short* __restrict__ out2, int n2)
{
    const int ntot = n0 + n1 + n2;
    const int stride = (int)gridDim.x * 256;
    for (int idx = blockIdx.x * 256 + threadIdx.x; idx < ntot; idx += stride) {
        int i = idx;
        const float* in; unsigned short* out;
        if (i < n0)           { in = in0; out = out0; }
        else if (i < n0 + n1) { in = in1; out = out1; i -= n0; }
        else                  { in = in2; out = out2; i -= n0 + n1; }
        float4 v = reinterpret_cast<const float4*>(in)[i];
        ushort4 o;
        o.x = __bfloat16_as_ushort(f2bf(v.x));
        o.y = __bfloat16_as_ushort(f2bf(v.y));
        o.z = __bfloat16_as_ushort(f2bf(v.z));
        o.w = __bfloat16_as_ushort(f2bf(v.w));
        reinterpret_cast<ushort4*>(out)[i] = o;
    }
}

// ---------------------------------------------------------------------------
// MFMA GEMM core — single-buffered (r9/r11/r13 measured-best, FROZEN).
// Permanent lessons: gl_lds IS the coalescing mechanism (r10); async staging
// only (r12); (256,4) bound — (256,5) spills (r8); single-buffer 4-blk/CU
// beats dbuf 2-blk/CU at K=768 (r9 vs r6).
// ---------------------------------------------------------------------------
#define GEMM_CORE(As, Bs, Aptr, Bptr, m0, n0, K)                               \
    const int t = threadIdx.x;                                                 \
    const int w = t >> 6, lane = t & 63;                                       \
    const int wr = w >> 1, wc = w & 1;                                         \
    const int quad = lane >> 4, l16 = lane & 15;                               \
    f32x4_t acc[4][4] = {};                                                    \
    const int lrow = lane >> 3;                                                \
    const int scol = (((lane & 7) ^ (lrow & 7)) * 8);                          \
    _Pragma("unroll")                                                          \
    for (int j = 0; j < 4; ++j) {                                              \
        int R = j * 32 + w * 8;                                                \
        gl_lds16((Aptr) + (size_t)((m0) + R + lrow) * (K) + scol, &(As)[R * 64]); \
        gl_lds16((Bptr) + (size_t)((n0) + R + lrow) * (K) + scol, &(Bs)[R * 64]); \
    }                                                                          \
    for (int k0 = 0; k0 < (K); k0 += 64) {                                     \
        __syncthreads();   /* implicit vmcnt drain: tile k0 resident */        \
        _Pragma("unroll")                                                      \
        for (int ks = 0; ks < 64; ks += 32) {                                  \
            bf16x8_t af[4], bf_[4];                                            \
            _Pragma("unroll")                                                  \
            for (int tm = 0; tm < 4; ++tm)                                     \
                af[tm] = *(const bf16x8_t*)&(As)[(wr * 64 + tm * 16 + l16) * 64 \
                        + ((((ks >> 3) + quad) ^ (l16 & 7)) * 8)];             \
            _Pragma("unroll")                                                  \
            for (int tn = 0; tn < 4; ++tn)                                     \
                bf_[tn] = *(const bf16x8_t*)&(Bs)[(wc * 64 + tn * 16 + l16) * 64 \
                        + ((((ks >> 3) + quad) ^ (l16 & 7)) * 8)];             \
            _Pragma("unroll")                                                  \
            for (int tm = 0; tm < 4; ++tm)                                     \
                _Pragma("unroll")                                              \
                for (int tn = 0; tn < 4; ++tn)                                 \
                    acc[tm][tn] = __builtin_amdgcn_mfma_f32_16x16x32_bf16(     \
                        af[tm], bf_[tn], acc[tm][tn], 0, 0, 0);                \
        }                                                                      \
        __syncthreads();   /* all waves done reading tile k0 */                \
        if (k0 + 64 < (K)) {                                                   \
            _Pragma("unroll")                                                  \
            for (int j = 0; j < 4; ++j) {                                      \
                int R = j * 32 + w * 8;                                        \
                gl_lds16((Aptr) + (size_t)((m0) + R + lrow) * (K) + k0 + 64 + scol, \
                         &(As)[R * 64]);                                       \
                gl_lds16((Bptr) + (size_t)((n0) + R + lrow) * (K) + k0 + 64 + scol, \
                         &(Bs)[R * 64]);                                       \
            }                                                                  \
        }                                                                      \
    }

// ---------------------------------------------------------------------------
// Kernel 1: QKV projection -> q/k/v in [B,H,S,HD] bf16.  (FROZEN at r13)
// ---------------------------------------------------------------------------
__global__ __launch_bounds__(256, 4) void qkv_gemm_mfma(
    const short* __restrict__ A, const short* __restrict__ W,
    const float* __restrict__ bias,
    bf16* __restrict__ Q, bf16* __restrict__ Kp, bf16* __restrict__ Vp)
{
    __shared__ short As[128 * 64];   // 16 KB
    __shared__ short Bs[128 * 64];   // 16 KB
    const int bid = blockIdx.x;
    const int swz = (bid & 7) * (2304 / 8) + (bid >> 3);
    const int n0 = (swz % 18) * 128;
    const int m0 = (swz / 18) * 128;
    GEMM_CORE(As, Bs, A, W, m0, n0, 768)

    const int which = n0 / 768;
    const int h = ((n0 + wc * 64) % 768) >> 6;
    bf16* dst = (which == 0) ? Q : (which == 1) ? Kp : Vp;
    float bv[4];
#pragma unroll
    for (int tn = 0; tn < 4; ++tn) bv[tn] = bias[n0 + wc * 64 + tn * 16 + l16];
#pragma unroll
    for (int tm = 0; tm < 4; ++tm) {
#pragma unroll
        for (int r = 0; r < 4; ++r) {
            int m = m0 + wr * 64 + tm * 16 + quad * 4 + r;
            int b = m >> 9, s = m & 511;
            size_t rb = (((size_t)b * H_ + h) * S_ + s) * HD_;
#pragma unroll
            for (int tn = 0; tn < 4; ++tn)
                dst[rb + tn * 16 + l16] = f2bf(acc[tm][tn][r] + bv[tn]);
        }
    }
}

// ---------------------------------------------------------------------------
// Kernel 3: output projection, fp32 out.  (FROZEN at r13)
// ---------------------------------------------------------------------------
__global__ __launch_bounds__(256, 4) void proj_gemm_mfma(
    const short* __restrict__ A, const short* __restrict__ W,
    const float* __restrict__ bias, float* __restrict__ out)
{
    __shared__ short As[128 * 64];
    __shared__ short Bs[128 * 64];
    const int bid = blockIdx.x;
    const int swz = (bid & 7) * (768 / 8) + (bid >> 3);
    const int n0 = (swz % 6) * 128;
    const int m0 = (swz / 6) * 128;
    GEMM_CORE(As, Bs, A, W, m0, n0, 768)

    float bv[4];
#pragma unroll
    for (int tn = 0; tn < 4; ++tn) bv[tn] = bias[n0 + wc * 64 + tn * 16 + l16];
#pragma unroll
    for (int tm = 0; tm < 4; ++tm) {
#pragma unroll
        for (int r = 0; r < 4; ++r) {
            int m = m0 + wr * 64 + tm * 16 + quad * 4 + r;
#pragma unroll
            for (int tn = 0; tn < 4; ++tn)
                out[(size_t)m * 768 + n0 + wc * 64 + tn * 16 + l16] =
                    acc[tm][tn][r] + bv[tn];
        }
    }
}

// ---------------------------------------------------------------------------
// Kernel 2: MFMA flash attention — 8-wave pipelined (r14 measured-best,
// FROZEN).  512 thr = 8 waves x 16 q-rows, 24 waves/CU; chunk-XOR K
// swizzle; wave-private Ps rows; Vt [dim][key] stride 68; K/V loads for
// tile t+1 issued before tile t's compute; one barrier per tile; setprio
// around MFMA clusters.
// ---------------------------------------------------------------------------
#define QT 128
#define KT 64
#define PS 68
#define VS 68

__global__ __launch_bounds__(512, 4) void attn_mfma(
    const short* __restrict__ Qg, const short* __restrict__ Kg,
    const short* __restrict__ Vg, bf16* __restrict__ O)
{
    __shared__ short Ks[2][KT * 64];   // 16 KB
    __shared__ short Vt[2][64 * VS];   // 17 KB  [dim][key]
    __shared__ short Ps[QT * PS];      // 17 KB

    const int t = threadIdx.x;
    const int w = t >> 6, lane = t & 63;        // w in 0..7
    const int quad = lane >> 4, l16 = lane & 15;
    const int lrow = lane >> 3;
    const int scol = (((lane & 7) ^ (lrow & 7)) * 8);
    const int bid = blockIdx.x;
    const int bh = (bid & 7) + 8 * (bid >> 5);  // 4 q-tiles of a bh share an XCD
    const int qt = (bid >> 3) & 3;
    const int q0 = qt * QT;
    const size_t base = (size_t)bh * (S_ * HD_);
    const int wq = w * 16;                      // 16 q-rows per wave

    // Q fragments: direct global->reg, loop-invariant (8 VGPRs).
    bf16x8_t aq[2];
#pragma unroll
    for (int ksi = 0; ksi < 2; ++ksi)
        aq[ksi] = *(const bf16x8_t*)(Qg + base
            + (size_t)(q0 + wq + l16) * 64 + ksi * 32 + quad * 8);

    f32x4_t Oacc[4] = {};
    float lsum[4] = {};

    // prologue: stage K0 (one gl_lds16 per wave, swizzled) + V0 -> Vt[0]
    gl_lds16(Kg + base + (size_t)(w * 8 + lrow) * 64 + scol, &Ks[0][w * 8 * 64]);
    {
        bf16x8_t v0 = *(const bf16x8_t*)(Vg + base + (size_t)lane * 64 + w * 8);
#pragma unroll
        for (int i = 0; i < 8; ++i)
            Vt[0][(w * 8 + i) * VS + lane] = v0[i];
    }
    __syncthreads();

    for (int kt = 0; kt < 8; ++kt) {
        const int cur = kt & 1, nxt = cur ^ 1;
        bf16x8_t pv = {};
        if (kt < 7) {
            gl_lds16(Kg + base + (size_t)((kt + 1) * KT + w * 8 + lrow) * 64 + scol,
                     &Ks[nxt][w * 8 * 64]);
            pv = *(const bf16x8_t*)(Vg + base
                + (size_t)((kt + 1) * KT + lane) * 64 + w * 8);
        }

        // QK^T: per-wave S tile [16 queries x 64 keys]
        f32x4_t sc[4] = {};
        __builtin_amdgcn_s_setprio(1);
#pragma unroll
        for (int ks = 0; ks < 64; ks += 32) {
            bf16x8_t bk[4];
#pragma unroll
            for (int tn = 0; tn < 4; ++tn)
                bk[tn] = *(const bf16x8_t*)&Ks[cur][(tn * 16 + l16) * 64
                        + ((((ks >> 3) + quad) ^ (l16 & 7)) * 8)];
#pragma unroll
            for (int tn = 0; tn < 4; ++tn)
                sc[tn] = __builtin_amdgcn_mfma_f32_16x16x32_bf16(
                    aq[ks >> 5], bk[tn], sc[tn], 0, 0, 0);
        }
        __builtin_amdgcn_s_setprio(0);

        // p = exp(s * 0.125); per-lane row partials; P -> LDS bf16
#pragma unroll
        for (int r = 0; r < 4; ++r) {
            int row = wq + quad * 4 + r;
            float rs = 0.f;
#pragma unroll
            for (int tn = 0; tn < 4; ++tn) {
                float p = __expf(sc[tn][r] * 0.125f);
                rs += p;
                Ps[row * PS + tn * 16 + l16] = (short)__bfloat16_as_ushort(f2bf(p));
            }
            lsum[r] += rs;
        }
        // no barrier: Ps rows [wq, wq+16) are written and read by this wave only

        // PV: O[16 x 64] per wave
        __builtin_amdgcn_s_setprio(1);
#pragma unroll
        for (int ks = 0; ks < 64; ks += 32) {
            bf16x8_t ap, bv[4];
            ap = *(const bf16x8_t*)&Ps[(wq + l16) * PS + ks + quad * 8];
#pragma unroll
            for (int tn = 0; tn < 4; ++tn)
                bv[tn] = *(const bf16x8_t*)&Vt[cur][(tn * 16 + l16) * VS + ks + quad * 8];
#pragma unroll
            for (int tn = 0; tn < 4; ++tn)
                Oacc[tn] = __builtin_amdgcn_mfma_f32_16x16x32_bf16(
                    ap, bv[tn], Oacc[tn], 0, 0, 0);
        }
        __builtin_amdgcn_s_setprio(0);

        if (kt < 7) {
#pragma unroll
            for (int i = 0; i < 8; ++i)
                Vt[nxt][(w * 8 + i) * VS + lane] = pv[i];
        }
        __syncthreads();
    }

    // reduce row sums across 16 col-lanes, normalize, store
    float linv[4];
#pragma unroll
    for (int r = 0; r < 4; ++r) {
        float v = lsum[r];
        v += __shfl_xor(v, 1, 64);
        v += __shfl_xor(v, 2, 64);
        v += __shfl_xor(v, 4, 64);
        v += __shfl_xor(v, 8, 64);
        linv[r] = 1.f / v;
    }
    const int b = bh / H_, h = bh % H_;
#pragma unroll
    for (int r = 0; r < 4; ++r) {
        int row = q0 + wq + quad * 4 + r;
        size_t ob = ((size_t)b * S_ + row) * D_ + h * HD_;
#pragma unroll
        for (int tn = 0; tn < 4; ++tn)
            O[ob + tn * 16 + l16] = f2bf(Oacc[tn][r] * linv[r]);
    }
}

// ---------------------------------------------------------------------------
extern "C" void kernel_launch(void* const* d_in, const int* in_sizes, int n_in,
                              void* d_out, int out_size, void* d_ws, size_t ws_size,
                              hipStream_t stream) {
    const float* x      = (const float*)d_in[0];
    const float* qkv_w  = (const float*)d_in[1];
    const float* qkv_b  = (const float*)d_in[2];
    const float* proj_w = (const float*)d_in[3];
    const float* proj_b = (const float*)d_in[4];
    float* out = (float*)d_out;

    unsigned short* q     = (unsigned short*)d_ws;
    unsigned short* k     = q + QKV_ELEMS;
    unsigned short* v     = k + QKV_ELEMS;
    unsigned short* slot4 = v + QKV_ELEMS;          // x_bf, then attn-out
    unsigned short* wq    = slot4 + QKV_ELEMS;
    unsigned short* wp    = wq + 2304 * 768;

    // single fused conversion launch, grid-strided at 2048 blocks (G11)
    const int nx = 16384 * 768 / 4, nw1 = 2304 * 768 / 4, nw2 = 768 * 768 / 4;
    f2bf3_kernel<<<2048, 256, 0, stream>>>(
        x, slot4, nx, qkv_w, wq, nw1, proj_w, wp, nw2);

    qkv_gemm_mfma<<<dim3(2304), 256, 0, stream>>>(
        (const short*)slot4, (const short*)wq, qkv_b,
        (bf16*)q, (bf16*)k, (bf16*)v);

    attn_mfma<<<dim3(32 * 12 * 4), 512, 0, stream>>>(
        (const short*)q, (const short*)k, (const short*)v, (bf16*)slot4);

    proj_gemm_mfma<<<dim3(768), 256, 0, stream>>>(
        (const short*)slot4, (const short*)wp, proj_b, out);
}